// Round 6
// baseline (270.519 us; speedup 1.0000x reference)
//
#include <hip/hip_runtime.h>
#include <math.h>

namespace {

constexpr int kB   = 64;
constexpr int kCin = 8;
constexpr int kR   = 800;
constexpr int kNC  = 128;
constexpr int kO   = 16;
constexpr int CT   = 256;   // conversion kernel TPB
constexpr int MT   = 512;   // main kernel TPB
constexpr int NITER = 3;
constexpr size_t WS_NEEDED =
    (size_t)kNC * kO * kR * kCin * sizeof(unsigned short);  // 26,214,400 B

typedef _Float16 half2v __attribute__((ext_vector_type(2)));

__device__ __forceinline__ half2v u2h(unsigned int u) {
  union { unsigned int u; half2v h; } x;
  x.u = u;
  return x.h;
}

__device__ __forceinline__ unsigned short f2h(float f) {
  union { _Float16 h; unsigned short s; } x;
  x.h = (_Float16)f;
  return x.s;
}

// ---- W conversion: fp32 [c][r][i][o] -> fp16 [c][o][r][i] (uint4 = 8 i's) --
// Per-XCD W working set: 16 c x 204.8 KB = 3.3 MB < 4 MB L2 (verified R4).
__global__ __launch_bounds__(CT) void conv_w(const float* __restrict__ W,
                                             unsigned short* __restrict__ Wb) {
  __shared__ float tile[32 * 132];   // 32 r-rows x 128 cols (+4 pad)
  const int blk = blockIdx.x;        // c*25 + rt
  const int c  = blk / 25;
  const int rt = blk - c * 25;
  const int r0 = rt * 32;
  const int t  = threadIdx.x;

  // read: 1024 float4, fully coalesced
  const float4* src =
      reinterpret_cast<const float4*>(W + ((size_t)c * kR + r0) * kCin * kO);
  #pragma unroll
  for (int k2 = 0; k2 < 4; ++k2) {
    const int i4  = t + k2 * CT;
    const float4 v = src[i4];
    const int fi = i4 * 4, row = fi >> 7, pos = fi & 127;
    *reinterpret_cast<float4*>(&tile[row * 132 + pos]) = v;
  }
  __syncthreads();

  // write: o = t>>4, rl = (t&15)+16k -> 16 consecutive uint4 per o-group
  // (256 B dense per 16-lane group). LDS gather banks: (rl*4+o) mod 32 ->
  // 32 distinct banks, 2 lanes each = free.
  const int o = t >> 4;
  #pragma unroll
  for (int k2 = 0; k2 < 2; ++k2) {
    const int rl = (t & 15) + 16 * k2;
    unsigned int pk[4];
    #pragma unroll
    for (int q = 0; q < 4; ++q) {
      const unsigned int lo = f2h(tile[rl * 132 + (2 * q + 0) * 16 + o]);
      const unsigned int hi = f2h(tile[rl * 132 + (2 * q + 1) * 16 + o]);
      pk[q] = lo | (hi << 16);
    }
    uint4* dst = reinterpret_cast<uint4*>(Wb) +
                 ((size_t)(c * kO + o) * kR + (r0 + rl));
    *dst = make_uint4(pk[0], pk[1], pk[2], pk[3]);
  }
}

// ---------------- main: priors in registers + fused routing ----------------
template <bool F16W>
__global__ __launch_bounds__(MT, 4) void caps_route(
    const float* __restrict__ x, const float* __restrict__ W,
    const unsigned short* __restrict__ Wb, float* __restrict__ out) {
  constexpr int RST = 19;               // 17 cols + pad
  __shared__ float red[128 * RST];      // 9.5 KB
  __shared__ float red2[8 * RST];
  __shared__ float shs[20];

  const int t = threadIdx.x;
  // XCD swizzle: consecutive resident blocks on one XCD share c.
  const int j   = blockIdx.x;
  const int xcd = j & 7;
  const int k   = j >> 3;               // 0..1023
  const int c   = ((k >> 6) << 3) + xcd;
  const int b   = k & 63;

  const float* xb  = x + (size_t)b * kCin * kR;
  const bool  has2 = (t < kR - MT);     // t < 288 owns second row r2
  const int   r1   = t, r2 = MT + t;

  float P1[kO], P2[kO];

  // -------- Phase 1: priors straight into registers (no LDS, no barrier) ---
  {
    float xa[kCin];
    #pragma unroll
    for (int i = 0; i < kCin; ++i) xa[i] = xb[i * kR + r1];
    if (F16W) {
      half2v xp[4];
      #pragma unroll
      for (int q = 0; q < 4; ++q)
        xp[q] = half2v{(_Float16)xa[2 * q], (_Float16)xa[2 * q + 1]};
      const uint4* Wc = reinterpret_cast<const uint4*>(Wb) + (size_t)c * kO * kR;
      #pragma unroll
      for (int o = 0; o < kO; ++o) {
        const uint4 w = Wc[(size_t)o * kR + r1];   // 16B coalesced, L2-hit
        float acc = __builtin_amdgcn_fdot2(u2h(w.x), xp[0], 0.f, false);
        acc = __builtin_amdgcn_fdot2(u2h(w.y), xp[1], acc, false);
        acc = __builtin_amdgcn_fdot2(u2h(w.z), xp[2], acc, false);
        acc = __builtin_amdgcn_fdot2(u2h(w.w), xp[3], acc, false);
        P1[o] = acc;
      }
    } else {
      const float* Wc = W + ((size_t)c * kR + r1) * kCin * kO;
      #pragma unroll
      for (int o = 0; o < kO; ++o) {
        float acc = 0.f;
        #pragma unroll
        for (int i = 0; i < kCin; ++i) acc += xa[i] * Wc[i * kO + o];
        P1[o] = acc;
      }
    }
  }
  if (has2) {
    float xa[kCin];
    #pragma unroll
    for (int i = 0; i < kCin; ++i) xa[i] = xb[i * kR + r2];
    if (F16W) {
      half2v xp[4];
      #pragma unroll
      for (int q = 0; q < 4; ++q)
        xp[q] = half2v{(_Float16)xa[2 * q], (_Float16)xa[2 * q + 1]};
      const uint4* Wc = reinterpret_cast<const uint4*>(Wb) + (size_t)c * kO * kR;
      #pragma unroll
      for (int o = 0; o < kO; ++o) {
        const uint4 w = Wc[(size_t)o * kR + r2];
        float acc = __builtin_amdgcn_fdot2(u2h(w.x), xp[0], 0.f, false);
        acc = __builtin_amdgcn_fdot2(u2h(w.y), xp[1], acc, false);
        acc = __builtin_amdgcn_fdot2(u2h(w.z), xp[2], acc, false);
        acc = __builtin_amdgcn_fdot2(u2h(w.w), xp[3], acc, false);
        P2[o] = acc;
      }
    } else {
      const float* Wc = W + ((size_t)c * kR + r2) * kCin * kO;
      #pragma unroll
      for (int o = 0; o < kO; ++o) {
        float acc = 0.f;
        #pragma unroll
        for (int i = 0; i < kCin; ++i) acc += xa[i] * Wc[i * kO + o];
        P2[o] = acc;
      }
    }
  } else {
    #pragma unroll
    for (int o = 0; o < kO; ++o) P2[o] = 0.f;
  }

  // -------- Phase 2: 3 routing iterations ----------------------------------
  // No max-subtraction: logits start at 0, |delta| small -> exp safe in fp32.
  float l1 = 0.f, l2 = 0.f;
  #pragma unroll
  for (int it = 0; it < NITER; ++it) {
    const float e1 = (it == 0) ? 1.f : __expf(l1);
    const float e2 = has2 ? ((it == 0) ? 1.f : __expf(l2)) : 0.f;

    float sp[kO + 1];
    sp[kO] = e1 + e2;
    #pragma unroll
    for (int o = 0; o < kO; ++o) sp[o] = e1 * P1[o] + e2 * P2[o];

    // fold 4 lanes -> 1 row, 128 rows total
    #pragma unroll
    for (int v = 0; v <= kO; ++v) {
      sp[v] += __shfl_xor(sp[v], 1, 64);
      sp[v] += __shfl_xor(sp[v], 2, 64);
    }
    if ((t & 3) == 0) {
      const int row = t >> 2;
      #pragma unroll
      for (int v = 0; v <= kO; ++v) red[row * RST + v] = sp[v];
    }
    __syncthreads();

    if (t < 136) {                       // 8 q-groups x 17 cols
      const int q = t / 17, col = t - q * 17;
      float a = 0.f;
      #pragma unroll
      for (int rr = 0; rr < 16; ++rr) a += red[(q * 16 + rr) * RST + col];
      red2[q * RST + col] = a;
    }
    __syncthreads();
    if (t < 17) {
      float a = 0.f;
      #pragma unroll
      for (int q = 0; q < 8; ++q) a += red2[q * RST + t];
      shs[t] = a;
    }
    __syncthreads();

    // squash, redundantly per thread: v[o] = shs[o] * g
    const float Zi = 1.f / shs[kO];
    float ss = 0.f;
    #pragma unroll
    for (int o = 0; o < kO; ++o) ss += shs[o] * shs[o];
    const float sn = ss * Zi * Zi;
    const float g  = Zi * sqrtf(sn) / (1.f + sn);

    if (it < NITER - 1) {
      float d1 = 0.f, d2 = 0.f;
      #pragma unroll
      for (int o = 0; o < kO; ++o) {
        d1 += P1[o] * shs[o];
        d2 += P2[o] * shs[o];
      }
      l1 += d1 * g;
      if (has2) l2 += d2 * g;
    } else {
      if (t < kO) out[(size_t)b * kO * kNC + t * kNC + c] = shs[t] * g;
    }
  }
}

}  // namespace

extern "C" void kernel_launch(void* const* d_in, const int* in_sizes, int n_in,
                              void* d_out, int out_size, void* d_ws, size_t ws_size,
                              hipStream_t stream) {
  const float* x = (const float*)d_in[0];   // [64, 8, 800] fp32
  const float* W = (const float*)d_in[1];   // [128, 800, 8, 16] fp32
  float* out = (float*)d_out;               // [64, 16, 128] fp32
  (void)in_sizes; (void)n_in; (void)out_size;

  const int grid = kNC * kB;                // 8192 blocks: (c, b)
  if (ws_size >= WS_NEEDED) {
    unsigned short* Wb = (unsigned short*)d_ws;
    conv_w<<<dim3(kNC * 25), dim3(CT), 0, stream>>>(W, Wb);
    caps_route<true><<<dim3(grid), dim3(MT), 0, stream>>>(x, W, Wb, out);
  } else {
    caps_route<false><<<dim3(grid), dim3(MT), 0, stream>>>(x, W, nullptr, out);
  }
}

// Round 7
// 249.349 us; speedup vs baseline: 1.0849x; 1.0849x over previous
//
#include <hip/hip_runtime.h>
#include <math.h>

namespace {

constexpr int kB   = 64;
constexpr int kCin = 8;
constexpr int kR   = 800;
constexpr int kNC  = 128;
constexpr int kO   = 16;
constexpr int CT   = 256;   // conversion kernel TPB
constexpr int MT   = 512;   // main kernel TPB
constexpr int NITER = 3;
constexpr size_t WS_NEEDED =
    (size_t)kNC * kO * kR * kCin * sizeof(unsigned short);  // 26,214,400 B

typedef _Float16 half2v __attribute__((ext_vector_type(2)));

__device__ __forceinline__ half2v u2h(unsigned int u) {
  union { unsigned int u; half2v h; } x;
  x.u = u;
  return x.h;
}

__device__ __forceinline__ unsigned short f2h(float f) {
  union { _Float16 h; unsigned short s; } x;
  x.h = (_Float16)f;
  return x.s;
}

// DPP quad-perm adds: xor1 = perm{1,0,3,2} = 0xB1, xor2 = perm{2,3,0,1} = 0x4E.
// VALU-pipe cross-lane (no ds_swizzle -> keeps the LDS pipe free).
__device__ __forceinline__ float dpp_xor1_add(float v) {
  const int o = __builtin_amdgcn_mov_dpp(__float_as_int(v), 0xB1, 0xF, 0xF, true);
  return v + __int_as_float(o);
}
__device__ __forceinline__ float dpp_xor2_add(float v) {
  const int o = __builtin_amdgcn_mov_dpp(__float_as_int(v), 0x4E, 0xF, 0xF, true);
  return v + __int_as_float(o);
}

// ---- W conversion: fp32 [c][r][i][o] -> fp16 [c][o][r][i] (uint4 = 8 i's) --
// 80-row tiles: 10 coalesced float4 reads + 5 mostly-contiguous uint4 writes
// per thread; LDS gather is 2-way-bank (free).
__global__ __launch_bounds__(CT) void conv_w(const float* __restrict__ W,
                                             unsigned short* __restrict__ Wb) {
  __shared__ float tile[80 * 132];   // 80 r-rows x 128 cols (+4 pad) = 42.2 KB
  const int blk = blockIdx.x;        // c*10 + rt
  const int c  = blk / 10;
  const int rt = blk - c * 10;
  const int r0 = rt * 80;
  const int t  = threadIdx.x;

  const float4* src =
      reinterpret_cast<const float4*>(W + ((size_t)c * kR + r0) * kCin * kO);
  #pragma unroll
  for (int k2 = 0; k2 < 10; ++k2) {
    const int i4  = t + k2 * CT;         // 0..2559 float4s, coalesced
    const float4 v = src[i4];
    const int fi = i4 * 4, row = fi >> 7, pos = fi & 127;
    *reinterpret_cast<float4*>(&tile[row * 132 + pos]) = v;
  }
  __syncthreads();

  const int o = t >> 4;
  #pragma unroll
  for (int k2 = 0; k2 < 5; ++k2) {
    const int rl = (t & 15) + 16 * k2;
    unsigned int pk[4];
    #pragma unroll
    for (int q = 0; q < 4; ++q) {
      const unsigned int lo = f2h(tile[rl * 132 + (2 * q + 0) * 16 + o]);
      const unsigned int hi = f2h(tile[rl * 132 + (2 * q + 1) * 16 + o]);
      pk[q] = lo | (hi << 16);
    }
    uint4* dst = reinterpret_cast<uint4*>(Wb) +
                 ((size_t)(c * kO + o) * kR + (r0 + rl));
    *dst = make_uint4(pk[0], pk[1], pk[2], pk[3]);
  }
}

// ---------------- main: priors in registers + fused routing ----------------
template <bool F16W>
__global__ __launch_bounds__(MT, 4) void caps_route(
    const float* __restrict__ x, const float* __restrict__ W,
    const unsigned short* __restrict__ Wb, float* __restrict__ out) {
  constexpr int RST = 20;               // 17 cols + 3 pad (16B-aligned rows)
  __shared__ float red[128 * RST];      // 10 KB
  __shared__ float red2[8 * RST];
  __shared__ float shs[20];

  const int t = threadIdx.x;
  // XCD swizzle: consecutive resident blocks on one XCD share c.
  const int j   = blockIdx.x;
  const int xcd = j & 7;
  const int k   = j >> 3;               // 0..1023
  const int c   = ((k >> 6) << 3) + xcd;
  const int b   = k & 63;

  const float* xb  = x + (size_t)b * kCin * kR;
  const bool  has2 = (t < kR - MT);     // t < 288 owns second row r2
  const int   r1   = t, r2 = MT + t;

  float P1[kO], P2[kO];

  // -------- Phase 1: priors straight into registers (no LDS, no barrier) ---
  {
    float xa[kCin];
    #pragma unroll
    for (int i = 0; i < kCin; ++i) xa[i] = xb[i * kR + r1];
    if (F16W) {
      half2v xp[4];
      #pragma unroll
      for (int q = 0; q < 4; ++q)
        xp[q] = half2v{(_Float16)xa[2 * q], (_Float16)xa[2 * q + 1]};
      const uint4* Wc = reinterpret_cast<const uint4*>(Wb) + (size_t)c * kO * kR;
      #pragma unroll
      for (int o = 0; o < kO; ++o) {
        const uint4 w = Wc[(size_t)o * kR + r1];   // 16B coalesced, L2-hit
        float acc = __builtin_amdgcn_fdot2(u2h(w.x), xp[0], 0.f, false);
        acc = __builtin_amdgcn_fdot2(u2h(w.y), xp[1], acc, false);
        acc = __builtin_amdgcn_fdot2(u2h(w.z), xp[2], acc, false);
        acc = __builtin_amdgcn_fdot2(u2h(w.w), xp[3], acc, false);
        P1[o] = acc;
      }
    } else {
      const float* Wc = W + ((size_t)c * kR + r1) * kCin * kO;
      #pragma unroll
      for (int o = 0; o < kO; ++o) {
        float acc = 0.f;
        #pragma unroll
        for (int i = 0; i < kCin; ++i) acc += xa[i] * Wc[i * kO + o];
        P1[o] = acc;
      }
    }
  }
  if (has2) {
    float xa[kCin];
    #pragma unroll
    for (int i = 0; i < kCin; ++i) xa[i] = xb[i * kR + r2];
    if (F16W) {
      half2v xp[4];
      #pragma unroll
      for (int q = 0; q < 4; ++q)
        xp[q] = half2v{(_Float16)xa[2 * q], (_Float16)xa[2 * q + 1]};
      const uint4* Wc = reinterpret_cast<const uint4*>(Wb) + (size_t)c * kO * kR;
      #pragma unroll
      for (int o = 0; o < kO; ++o) {
        const uint4 w = Wc[(size_t)o * kR + r2];
        float acc = __builtin_amdgcn_fdot2(u2h(w.x), xp[0], 0.f, false);
        acc = __builtin_amdgcn_fdot2(u2h(w.y), xp[1], acc, false);
        acc = __builtin_amdgcn_fdot2(u2h(w.z), xp[2], acc, false);
        acc = __builtin_amdgcn_fdot2(u2h(w.w), xp[3], acc, false);
        P2[o] = acc;
      }
    } else {
      const float* Wc = W + ((size_t)c * kR + r2) * kCin * kO;
      #pragma unroll
      for (int o = 0; o < kO; ++o) {
        float acc = 0.f;
        #pragma unroll
        for (int i = 0; i < kCin; ++i) acc += xa[i] * Wc[i * kO + o];
        P2[o] = acc;
      }
    }
  } else {
    #pragma unroll
    for (int o = 0; o < kO; ++o) P2[o] = 0.f;
  }

  // -------- Phase 2: 3 routing iterations ----------------------------------
  // No max-subtraction: logits start at 0, |delta| small -> exp safe in fp32.
  float l1 = 0.f, l2 = 0.f;
  #pragma unroll
  for (int it = 0; it < NITER; ++it) {
    const float e1 = (it == 0) ? 1.f : __expf(l1);
    const float e2 = has2 ? ((it == 0) ? 1.f : __expf(l2)) : 0.f;

    float sp[kO + 1];
    sp[kO] = e1 + e2;
    #pragma unroll
    for (int o = 0; o < kO; ++o) sp[o] = e1 * P1[o] + e2 * P2[o];

    // fold 4 lanes -> 1 row via DPP quad-perm (VALU pipe, no LDS)
    #pragma unroll
    for (int v = 0; v <= kO; ++v) {
      sp[v] = dpp_xor1_add(sp[v]);
      sp[v] = dpp_xor2_add(sp[v]);
    }
    if ((t & 3) == 0) {
      float* row = &red[(t >> 2) * RST];
      *reinterpret_cast<float4*>(row +  0) = make_float4(sp[0], sp[1], sp[2], sp[3]);
      *reinterpret_cast<float4*>(row +  4) = make_float4(sp[4], sp[5], sp[6], sp[7]);
      *reinterpret_cast<float4*>(row +  8) = make_float4(sp[8], sp[9], sp[10], sp[11]);
      *reinterpret_cast<float4*>(row + 12) = make_float4(sp[12], sp[13], sp[14], sp[15]);
      row[16] = sp[16];
    }
    __syncthreads();

    if (t < 136) {                       // 8 q-groups x 17 cols
      const int q = t / 17, col = t - q * 17;
      float a = 0.f;
      #pragma unroll
      for (int rr = 0; rr < 16; ++rr) a += red[(q * 16 + rr) * RST + col];
      red2[q * RST + col] = a;
    }
    __syncthreads();
    if (t < 17) {
      float a = 0.f;
      #pragma unroll
      for (int q = 0; q < 8; ++q) a += red2[q * RST + t];
      shs[t] = a;
    }
    __syncthreads();

    // squash, redundantly per thread: v[o] = shs[o] * g
    const float Zi = 1.f / shs[kO];
    float ss = 0.f;
    #pragma unroll
    for (int o = 0; o < kO; ++o) ss += shs[o] * shs[o];
    const float sn = ss * Zi * Zi;
    const float g  = Zi * sqrtf(sn) / (1.f + sn);

    if (it < NITER - 1) {
      float d1 = 0.f, d2 = 0.f;
      #pragma unroll
      for (int o = 0; o < kO; ++o) {
        d1 += P1[o] * shs[o];
        d2 += P2[o] * shs[o];
      }
      l1 += d1 * g;
      if (has2) l2 += d2 * g;
    } else {
      if (t < kO) out[(size_t)b * kO * kNC + t * kNC + c] = shs[t] * g;
    }
  }
}

}  // namespace

extern "C" void kernel_launch(void* const* d_in, const int* in_sizes, int n_in,
                              void* d_out, int out_size, void* d_ws, size_t ws_size,
                              hipStream_t stream) {
  const float* x = (const float*)d_in[0];   // [64, 8, 800] fp32
  const float* W = (const float*)d_in[1];   // [128, 800, 8, 16] fp32
  float* out = (float*)d_out;               // [64, 16, 128] fp32
  (void)in_sizes; (void)n_in; (void)out_size;

  const int grid = kNC * kB;                // 8192 blocks: (c, b)
  if (ws_size >= WS_NEEDED) {
    unsigned short* Wb = (unsigned short*)d_ws;
    conv_w<<<dim3(kNC * 10), dim3(CT), 0, stream>>>(W, Wb);
    caps_route<true><<<dim3(grid), dim3(MT), 0, stream>>>(x, W, Wb, out);
  } else {
    caps_route<false><<<dim3(grid), dim3(MT), 0, stream>>>(x, W, nullptr, out);
  }
}

// Round 8
// 248.101 us; speedup vs baseline: 1.0904x; 1.0050x over previous
//
#include <hip/hip_runtime.h>
#include <math.h>

namespace {

constexpr int kB   = 64;
constexpr int kCin = 8;
constexpr int kR   = 800;
constexpr int kNC  = 128;
constexpr int kO   = 16;
constexpr int CT   = 256;   // conversion kernel TPB
constexpr int MT   = 512;   // main kernel TPB
constexpr int NITER = 3;
constexpr size_t WS_NEEDED =
    (size_t)kNC * kO * kR * kCin * sizeof(unsigned short);  // 26,214,400 B

typedef _Float16 half2v __attribute__((ext_vector_type(2)));

__device__ __forceinline__ half2v u2h(unsigned int u) {
  union { unsigned int u; half2v h; } x;
  x.u = u;
  return x.h;
}

__device__ __forceinline__ unsigned short f2h(float f) {
  union { _Float16 h; unsigned short s; } x;
  x.h = (_Float16)f;
  return x.s;
}

// DPP quad-perm adds: xor1 = perm{1,0,3,2} = 0xB1, xor2 = perm{2,3,0,1} = 0x4E.
__device__ __forceinline__ float dpp_xor1_add(float v) {
  const int o = __builtin_amdgcn_mov_dpp(__float_as_int(v), 0xB1, 0xF, 0xF, true);
  return v + __int_as_float(o);
}
__device__ __forceinline__ float dpp_xor2_add(float v) {
  const int o = __builtin_amdgcn_mov_dpp(__float_as_int(v), 0x4E, 0xF, 0xF, true);
  return v + __int_as_float(o);
}

// ---- W conversion: fp32 [c][r][i][o] -> fp16 [c][o][r][i] (uint4 = 8 i's) --
__global__ __launch_bounds__(CT) void conv_w(const float* __restrict__ W,
                                             unsigned short* __restrict__ Wb) {
  __shared__ float tile[80 * 132];   // 80 r-rows x 128 cols (+4 pad) = 42.2 KB
  const int blk = blockIdx.x;        // c*10 + rt
  const int c  = blk / 10;
  const int rt = blk - c * 10;
  const int r0 = rt * 80;
  const int t  = threadIdx.x;

  const float4* src =
      reinterpret_cast<const float4*>(W + ((size_t)c * kR + r0) * kCin * kO);
  #pragma unroll
  for (int k2 = 0; k2 < 10; ++k2) {
    const int i4  = t + k2 * CT;         // coalesced float4s
    const float4 v = src[i4];
    const int fi = i4 * 4, row = fi >> 7, pos = fi & 127;
    *reinterpret_cast<float4*>(&tile[row * 132 + pos]) = v;
  }
  __syncthreads();

  const int o = t >> 4;
  #pragma unroll
  for (int k2 = 0; k2 < 5; ++k2) {
    const int rl = (t & 15) + 16 * k2;
    unsigned int pk[4];
    #pragma unroll
    for (int q = 0; q < 4; ++q) {
      const unsigned int lo = f2h(tile[rl * 132 + (2 * q + 0) * 16 + o]);
      const unsigned int hi = f2h(tile[rl * 132 + (2 * q + 1) * 16 + o]);
      pk[q] = lo | (hi << 16);
    }
    uint4* dst = reinterpret_cast<uint4*>(Wb) +
                 ((size_t)(c * kO + o) * kR + (r0 + rl));
    *dst = make_uint4(pk[0], pk[1], pk[2], pk[3]);
  }
}

// -------- main: nb=2 — each W row load feeds two b's; fused reduction ------
__global__ __launch_bounds__(MT, 4) void caps_route(
    const float* __restrict__ x, const unsigned short* __restrict__ Wb,
    float* __restrict__ out) {
  constexpr int RST = 36;               // 34 cols + 2 pad (16B-aligned rows)
  __shared__ float red[128 * RST];      // 18.4 KB
  __shared__ float red2[8 * RST];
  __shared__ float shs[36];

  const int t = threadIdx.x;
  // XCD swizzle: 32 consecutive k's share c -> temporal L2 locality per XCD.
  const int j   = blockIdx.x;
  const int xcd = j & 7;
  const int k   = j >> 3;               // 0..511
  const int c   = ((k >> 5) << 3) + xcd;
  const int bg  = k & 31;
  const int b0  = bg * 2, b1 = b0 + 1;

  const float* x0 = x + (size_t)b0 * kCin * kR;
  const float* x1 = x + (size_t)b1 * kCin * kR;
  const bool  has2 = (t < kR - MT);     // t < 288 owns second row r2
  const int   r1   = t, r2 = MT + t;

  // P[b][row][o]
  float P01[kO], P02[kO], P11[kO], P12[kO];
  #pragma unroll
  for (int o = 0; o < kO; ++o) { P02[o] = 0.f; P12[o] = 0.f; }

  // -------- Phase 1: one W-row load serves both b's -------------------------
  const uint4* Wc = reinterpret_cast<const uint4*>(Wb) + (size_t)c * kO * kR;
  {
    half2v xp0[4], xp1[4];
    #pragma unroll
    for (int q = 0; q < 4; ++q) {
      xp0[q] = half2v{(_Float16)x0[(2*q) * kR + r1], (_Float16)x0[(2*q+1) * kR + r1]};
      xp1[q] = half2v{(_Float16)x1[(2*q) * kR + r1], (_Float16)x1[(2*q+1) * kR + r1]};
    }
    #pragma unroll
    for (int o = 0; o < kO; ++o) {
      const uint4 w = Wc[(size_t)o * kR + r1];   // 16B coalesced, L2-hit
      float a0 = __builtin_amdgcn_fdot2(u2h(w.x), xp0[0], 0.f, false);
      float a1 = __builtin_amdgcn_fdot2(u2h(w.x), xp1[0], 0.f, false);
      a0 = __builtin_amdgcn_fdot2(u2h(w.y), xp0[1], a0, false);
      a1 = __builtin_amdgcn_fdot2(u2h(w.y), xp1[1], a1, false);
      a0 = __builtin_amdgcn_fdot2(u2h(w.z), xp0[2], a0, false);
      a1 = __builtin_amdgcn_fdot2(u2h(w.z), xp1[2], a1, false);
      a0 = __builtin_amdgcn_fdot2(u2h(w.w), xp0[3], a0, false);
      a1 = __builtin_amdgcn_fdot2(u2h(w.w), xp1[3], a1, false);
      P01[o] = a0;
      P11[o] = a1;
    }
  }
  if (has2) {
    half2v xp0[4], xp1[4];
    #pragma unroll
    for (int q = 0; q < 4; ++q) {
      xp0[q] = half2v{(_Float16)x0[(2*q) * kR + r2], (_Float16)x0[(2*q+1) * kR + r2]};
      xp1[q] = half2v{(_Float16)x1[(2*q) * kR + r2], (_Float16)x1[(2*q+1) * kR + r2]};
    }
    #pragma unroll
    for (int o = 0; o < kO; ++o) {
      const uint4 w = Wc[(size_t)o * kR + r2];
      float a0 = __builtin_amdgcn_fdot2(u2h(w.x), xp0[0], 0.f, false);
      float a1 = __builtin_amdgcn_fdot2(u2h(w.x), xp1[0], 0.f, false);
      a0 = __builtin_amdgcn_fdot2(u2h(w.y), xp0[1], a0, false);
      a1 = __builtin_amdgcn_fdot2(u2h(w.y), xp1[1], a1, false);
      a0 = __builtin_amdgcn_fdot2(u2h(w.z), xp0[2], a0, false);
      a1 = __builtin_amdgcn_fdot2(u2h(w.z), xp1[2], a1, false);
      a0 = __builtin_amdgcn_fdot2(u2h(w.w), xp0[3], a0, false);
      a1 = __builtin_amdgcn_fdot2(u2h(w.w), xp1[3], a1, false);
      P02[o] = a0;
      P12[o] = a1;
    }
  }

  // -------- Phase 2: 3 routing iterations, b0+b1 fused ----------------------
  // cols: [0..15]=s(b0), [16..31]=s(b1), [32]=Z0, [33]=Z1.
  float l01 = 0.f, l02 = 0.f, l11 = 0.f, l12 = 0.f;
  #pragma unroll
  for (int it = 0; it < NITER; ++it) {
    const float e01 = (it == 0) ? 1.f : __expf(l01);
    const float e02 = has2 ? ((it == 0) ? 1.f : __expf(l02)) : 0.f;
    const float e11 = (it == 0) ? 1.f : __expf(l11);
    const float e12 = has2 ? ((it == 0) ? 1.f : __expf(l12)) : 0.f;

    float sp[34];
    #pragma unroll
    for (int o = 0; o < kO; ++o) {
      sp[o]      = e01 * P01[o] + e02 * P02[o];
      sp[16 + o] = e11 * P11[o] + e12 * P12[o];
    }
    sp[32] = e01 + e02;
    sp[33] = e11 + e12;

    // fold 4 lanes -> 1 row via DPP quad-perm (VALU pipe)
    #pragma unroll
    for (int v = 0; v < 34; ++v) {
      sp[v] = dpp_xor1_add(sp[v]);
      sp[v] = dpp_xor2_add(sp[v]);
    }
    if ((t & 3) == 0) {
      float* row = &red[(t >> 2) * RST];
      #pragma unroll
      for (int q = 0; q < 8; ++q)
        *reinterpret_cast<float4*>(row + 4 * q) =
            make_float4(sp[4*q], sp[4*q+1], sp[4*q+2], sp[4*q+3]);
      row[32] = sp[32];
      row[33] = sp[33];
    }
    __syncthreads();

    if (t < 272) {                       // 8 q-groups x 34 cols
      const int q = t / 34, col = t - q * 34;
      float a = 0.f;
      #pragma unroll
      for (int rr = 0; rr < 16; ++rr) a += red[(q * 16 + rr) * RST + col];
      red2[q * RST + col] = a;
    }
    __syncthreads();
    if (t < 34) {
      float a = 0.f;
      #pragma unroll
      for (int q = 0; q < 8; ++q) a += red2[q * RST + t];
      shs[t] = a;
    }
    __syncthreads();

    // squash per b (redundant per thread)
    const float Zi0 = 1.f / shs[32];
    const float Zi1 = 1.f / shs[33];
    float ss0 = 0.f, ss1 = 0.f;
    #pragma unroll
    for (int o = 0; o < kO; ++o) {
      ss0 += shs[o] * shs[o];
      ss1 += shs[16 + o] * shs[16 + o];
    }
    const float sn0 = ss0 * Zi0 * Zi0;
    const float sn1 = ss1 * Zi1 * Zi1;
    const float g0  = Zi0 * sqrtf(sn0) / (1.f + sn0);
    const float g1  = Zi1 * sqrtf(sn1) / (1.f + sn1);

    if (it < NITER - 1) {
      float d01 = 0.f, d02 = 0.f, d11 = 0.f, d12 = 0.f;
      #pragma unroll
      for (int o = 0; o < kO; ++o) {
        d01 += P01[o] * shs[o];
        d02 += P02[o] * shs[o];
        d11 += P11[o] * shs[16 + o];
        d12 += P12[o] * shs[16 + o];
      }
      l01 += d01 * g0;
      l11 += d11 * g1;
      if (has2) { l02 += d02 * g0; l12 += d12 * g1; }
    } else {
      // out[b, o, c], shape [B, O, NC]
      if (t < kO) {
        out[(size_t)b0 * kO * kNC + t * kNC + c] = shs[t] * g0;
      } else if (t < 2 * kO) {
        out[(size_t)b1 * kO * kNC + (t - kO) * kNC + c] = shs[t] * g1;
      }
    }
  }
}

// ---- fallback (no workspace): fp32 W direct, nb=1 (correctness path) ------
__global__ __launch_bounds__(MT, 4) void caps_route_f32(
    const float* __restrict__ x, const float* __restrict__ W,
    float* __restrict__ out) {
  constexpr int RST = 20;
  __shared__ float red[128 * RST];
  __shared__ float red2[8 * RST];
  __shared__ float shs[20];

  const int t = threadIdx.x;
  const int j   = blockIdx.x;
  const int xcd = j & 7;
  const int k   = j >> 3;
  const int c   = ((k >> 6) << 3) + xcd;
  const int b   = k & 63;

  const float* xb  = x + (size_t)b * kCin * kR;
  const bool  has2 = (t < kR - MT);
  const int   r1   = t, r2 = MT + t;

  float P1[kO], P2[kO];
  #pragma unroll
  for (int o = 0; o < kO; ++o) P2[o] = 0.f;
  {
    float xa[kCin];
    #pragma unroll
    for (int i = 0; i < kCin; ++i) xa[i] = xb[i * kR + r1];
    const float* Wc = W + ((size_t)c * kR + r1) * kCin * kO;
    #pragma unroll
    for (int o = 0; o < kO; ++o) {
      float acc = 0.f;
      #pragma unroll
      for (int i = 0; i < kCin; ++i) acc += xa[i] * Wc[i * kO + o];
      P1[o] = acc;
    }
  }
  if (has2) {
    float xa[kCin];
    #pragma unroll
    for (int i = 0; i < kCin; ++i) xa[i] = xb[i * kR + r2];
    const float* Wc = W + ((size_t)c * kR + r2) * kCin * kO;
    #pragma unroll
    for (int o = 0; o < kO; ++o) {
      float acc = 0.f;
      #pragma unroll
      for (int i = 0; i < kCin; ++i) acc += xa[i] * Wc[i * kO + o];
      P2[o] = acc;
    }
  }

  float l1 = 0.f, l2 = 0.f;
  #pragma unroll
  for (int it = 0; it < NITER; ++it) {
    const float e1 = (it == 0) ? 1.f : __expf(l1);
    const float e2 = has2 ? ((it == 0) ? 1.f : __expf(l2)) : 0.f;
    float sp[kO + 1];
    sp[kO] = e1 + e2;
    #pragma unroll
    for (int o = 0; o < kO; ++o) sp[o] = e1 * P1[o] + e2 * P2[o];
    #pragma unroll
    for (int v = 0; v <= kO; ++v) {
      sp[v] = dpp_xor1_add(sp[v]);
      sp[v] = dpp_xor2_add(sp[v]);
    }
    if ((t & 3) == 0) {
      float* row = &red[(t >> 2) * RST];
      #pragma unroll
      for (int q = 0; q < 4; ++q)
        *reinterpret_cast<float4*>(row + 4 * q) =
            make_float4(sp[4*q], sp[4*q+1], sp[4*q+2], sp[4*q+3]);
      row[16] = sp[16];
    }
    __syncthreads();
    if (t < 136) {
      const int q = t / 17, col = t - q * 17;
      float a = 0.f;
      #pragma unroll
      for (int rr = 0; rr < 16; ++rr) a += red[(q * 16 + rr) * RST + col];
      red2[q * RST + col] = a;
    }
    __syncthreads();
    if (t < 17) {
      float a = 0.f;
      #pragma unroll
      for (int q = 0; q < 8; ++q) a += red2[q * RST + t];
      shs[t] = a;
    }
    __syncthreads();
    const float Zi = 1.f / shs[kO];
    float ss = 0.f;
    #pragma unroll
    for (int o = 0; o < kO; ++o) ss += shs[o] * shs[o];
    const float sn = ss * Zi * Zi;
    const float g  = Zi * sqrtf(sn) / (1.f + sn);
    if (it < NITER - 1) {
      float d1 = 0.f, d2 = 0.f;
      #pragma unroll
      for (int o = 0; o < kO; ++o) { d1 += P1[o] * shs[o]; d2 += P2[o] * shs[o]; }
      l1 += d1 * g;
      if (has2) l2 += d2 * g;
    } else {
      if (t < kO) out[(size_t)b * kO * kNC + t * kNC + c] = shs[t] * g;
    }
  }
}

}  // namespace

extern "C" void kernel_launch(void* const* d_in, const int* in_sizes, int n_in,
                              void* d_out, int out_size, void* d_ws, size_t ws_size,
                              hipStream_t stream) {
  const float* x = (const float*)d_in[0];   // [64, 8, 800] fp32
  const float* W = (const float*)d_in[1];   // [128, 800, 8, 16] fp32
  float* out = (float*)d_out;               // [64, 16, 128] fp32
  (void)in_sizes; (void)n_in; (void)out_size;

  if (ws_size >= WS_NEEDED) {
    unsigned short* Wb = (unsigned short*)d_ws;
    conv_w<<<dim3(kNC * 10), dim3(CT), 0, stream>>>(W, Wb);
    caps_route<<<dim3(kNC * kB / 2), dim3(MT), 0, stream>>>(x, Wb, out);
  } else {
    caps_route_f32<<<dim3(kNC * kB), dim3(MT), 0, stream>>>(x, W, out);
  }
}